// Round 9
// baseline (2811.593 us; speedup 1.0000x reference)
//
#include <hip/hip_runtime.h>
#include <math.h>

#define N 4096
#define STEPS 16384
#define WIN 64                 // steps resolved per barrier pair (full wave64)
#define NWIN (STEPS / WIN)
#define MBLK 1024
#define SBS64 65   // stride 65 ≡ 1 (mod 32): conflict-free row reads AND slice stores

// Workgroup barrier that does NOT drain vmcnt (LDS-only ordering between phases).
__device__ __forceinline__ void lgkm_barrier() {
  asm volatile("s_waitcnt lgkmcnt(0)\n\ts_barrier" ::: "memory");
}

// ---- prep: thr[t] = atanh(2u-1) in fp64; samemask[t] = 64-bit window dup mask ----
__global__ __launch_bounds__(256) void pre_kernel(const float* __restrict__ u,
                                                  const int* __restrict__ idx,
                                                  double* __restrict__ thr,
                                                  unsigned long long* __restrict__ samemask) {
  int t = blockIdx.x * 256 + threadIdx.x;
  if (t < STEPS) {
    float r = 2.0f * u[t] - 1.0f;          // exact same fp32 rounding as reference
    double rd = (double)r;
    thr[t] = 0.5 * log((1.0 + rd) / (1.0 - rd));   // r=-1 -> -inf (tie->+1 matches ref)
    int cbase = t & ~(WIN - 1);
    int my = idx[t];
    unsigned long long sm = 0ull;
    for (int q = 0; q < WIN; ++q)
      if (idx[cbase + q] == my) sm |= (1ull << q);   // includes self bit
    samemask[t] = sm;
  }
}

// ---- initial field: I0[row] = sum_k J[row,k]*m0[k] + h[row], fp64 accumulate ----
__global__ __launch_bounds__(256) void init_field_kernel(const float* __restrict__ J,
                                                         const float* __restrict__ h,
                                                         const float* __restrict__ m0,
                                                         double* __restrict__ I) {
  __shared__ double red[256];
  int row = blockIdx.x;
  const float4* Jr = (const float4*)(J + (size_t)row * N);
  const float4* mv = (const float4*)m0;
  double acc = 0.0;
  for (int q = threadIdx.x; q < N / 4; q += 256) {
    float4 a = Jr[q];
    float4 b = mv[q];
    acc += (double)(a.x * b.x) + (double)(a.y * b.y) +
           (double)(a.z * b.z) + (double)(a.w * b.w);
  }
  red[threadIdx.x] = acc;
  __syncthreads();
  for (int s = 128; s > 0; s >>= 1) {
    if (threadIdx.x < s) red[threadIdx.x] += red[threadIdx.x + s];
    __syncthreads();
  }
  if (threadIdx.x == 0) I[row] = red[0] + (double)h[row];
}

// ---- window-resolved Glauber chain: 1 workgroup, 1024 threads, WIN=64 ----
// R7 slim chain, window widened to the full wave (all 64 lanes = real steps):
//  P1(k): issue sliceA of G(k+1) [rows 0-31 x 64 cols, 32 vals/lane regs];
//         resolve 64 steps from STb[k&1] (ballot-bit signs, 64-bit samemask,
//         one conflict-free ds_read per flip); publish; store sliceA;
//         issue sliceB [rows 32-63]. Workers park at the barrier.
//  P2(k): all 1024 threads apply the F flipped rows (batches of 8);
//         wave0 then stores sliceB (wait overlaps apply). lgkm-only barriers.
// Halves barrier pairs / field reads / publish / terminal rounds vs WIN=32.
__global__ __launch_bounds__(MBLK) void pbit_kernel(const float* __restrict__ J,
                                                    const float* __restrict__ m0,
                                                    const int* __restrict__ idx,
                                                    const double* __restrict__ thr,
                                                    const unsigned long long* __restrict__ samemask,
                                                    const double* __restrict__ I0,
                                                    float* __restrict__ out) {
  __shared__ __align__(16) double field_lds[N];        // 32 KB master field
  __shared__ __align__(16) float m_lds[N];             // 16 KB spins
  __shared__ __align__(16) float STb[2][WIN * SBS64];  // double-buffered 64x64 blocks
  __shared__ __align__(16) int   pubi_lds[WIN];        // compacted flip rows
  __shared__ __align__(16) float pubd_lds[WIN];        // compacted deltas (+/-2)
  __shared__ int pubF_lds;                             // flip count

  const int tid = threadIdx.x;

  // owned field elements 4*tid..4*tid+3: fp64 registers + LDS write-through
  double i0, i1, i2, i3;
  {
    const double* ip = I0 + 4 * tid;
    i0 = ip[0]; i1 = ip[1]; i2 = ip[2]; i3 = ip[3];
    *(double2*)(field_lds + 4 * tid + 0) = make_double2(i0, i1);
    *(double2*)(field_lds + 4 * tid + 2) = make_double2(i2, i3);
  }
  ((float4*)m_lds)[tid] = ((const float4*)m0)[tid];

  const int t64 = tid & 63;        // step slot (wave0: all 64 lanes distinct)
  const int grow_r = tid >> 1;     // gather row slot within slice (0..31)
  const int ghalf = (tid & 1) * 32;  // gather col half

  // wave0 step-data pipeline (2 windows deep) + in-flight gather slice regs
  int mi = 0, ni = 0;
  unsigned long long msm = 0ull, nsm = 0ull;
  double mt = 0.0, nt = 0.0;
  float gva[32];
#pragma unroll
  for (int q = 0; q < 32; ++q) gva[q] = 0.f;

  if (tid < 64) {
    mi = idx[t64];       mt = thr[t64];       msm = samemask[t64];
    ni = idx[WIN + t64]; nt = thr[WIN + t64]; nsm = samemask[WIN + t64];
    // synchronous G(0) gather, both slices
    {
      int rowA = __shfl(mi, grow_r);
      const float* Ja = J + (size_t)rowA * N;
#pragma unroll
      for (int q = 0; q < 32; ++q) {
        int c = __shfl(mi, ghalf + q);
        STb[0][grow_r * SBS64 + ghalf + q] = Ja[c];
      }
      int rowB = __shfl(mi, 32 + grow_r);
      const float* Jc = J + (size_t)rowB * N;
#pragma unroll
      for (int q = 0; q < 32; ++q) {
        int c = __shfl(mi, ghalf + q);
        STb[0][(32 + grow_r) * SBS64 + ghalf + q] = Jc[c];
      }
    }
  }
  __syncthreads();

  for (int k = 0; k < NWIN; ++k) {
    // ---------------- P1: wave0 resolves 64 steps ----------------
    if (tid < 64) {
      // (a) issue sliceA of G(k+1): rows 0-31 from ni
      {
        int rowA = __shfl(ni, grow_r);
        const float* Jg = J + (size_t)rowA * N;
#pragma unroll
        for (int q = 0; q < 32; ++q) {
          int c = __shfl(ni, ghalf + q);
          gva[q] = Jg[c];
        }
      }
      // (b) step-data loads for window k+2
      int b2 = (k + 2) * WIN; if (b2 >= STEPS) b2 = 0;   // clamp: unused on tail
      int n2i = idx[b2 + t64];
      double n2t = thr[b2 + t64];
      unsigned long long n2sm = samemask[b2 + t64];
      // (c) flip-driven resolve from STb[k&1]: slim chain
      const float* SB = &STb[k & 1][0];
      double Ival = field_lds[mi];
      float mcur = m_lds[mi];
      float finals = 0.0f, finald = 0.0f;
      int conf = -1;
      bool locked = false;
      while (true) {
        bool sup = (Ival >= mt);                 // I >= atanh(r) <=> tanh(I) >= r
        float s = sup ? 1.0f : -1.0f;
        float dl = s - mcur;
        unsigned long long D = __ballot(sup);
        unsigned long long mask = __ballot(dl != 0.0f);
        unsigned long long gate = (conf >= 63) ? 0ull : ((~0ull) << (conf + 1));
        mask &= gate;
        if (mask == 0ull) {
          if (!locked) { finals = s; finald = 0.0f; }
          break;
        }
        int f = (int)__builtin_ctzll(mask);      // wave-uniform
        if (!locked && t64 <= f) { finals = s; finald = dl; locked = true; }
        // flip lane f: flipped => dl_f = 2*s_f; s_f from ballot bit
        float s_f  = ((D >> f) & 1ull) ? 1.0f : -1.0f;
        float dl_f = 2.0f * s_f;
        // Scol[f] for my lane = SB[f*SBS64 + t64]: conflict-free, f uniform
        float xcol = SB[f * SBS64 + t64];
        Ival += (double)(xcol * dl_f);            // exact product: dl in {-2,2}
        if ((msm >> f) & 1ull) mcur = s_f;        // same-idx step (incl. self)
        conf = f;
      }
      // (d) publish: compacted flip list + m updates (last occurrence wins)
      unsigned long long fm = __ballot(finald != 0.0f);
      {
        if (finald != 0.0f) {
          int pos = (int)__popcll(fm & ((1ull << t64) - 1ull));
          pubi_lds[pos] = mi;
          pubd_lds[pos] = finald;
        }
        bool mlo = ((msm >> t64) >> 1) == 0ull;   // no later same-idx step
        if (mlo) m_lds[mi] = finals;
        if (tid == 0) pubF_lds = (int)__popcll(fm);
      }
      // (e) store sliceA of G(k+1) (loads had resolve-length slack)
      {
        float* dst = &STb[(k + 1) & 1][grow_r * SBS64 + ghalf];
#pragma unroll
        for (int q = 0; q < 32; ++q) dst[q] = gva[q];
      }
      // (f) issue sliceB of G(k+1): rows 32-63 from ni (stored in P2)
      {
        int rowB = __shfl(ni, 32 + grow_r);
        const float* Jg = J + (size_t)rowB * N;
#pragma unroll
        for (int q = 0; q < 32; ++q) {
          int c = __shfl(ni, ghalf + q);
          gva[q] = Jg[c];
        }
      }
      // (g) rotate step-data pipeline
      mi = ni;  mt = nt;  msm = nsm;
      ni = n2i; nt = n2t; nsm = n2sm;
    }
    lgkm_barrier();

    // ---------------- P2: all threads apply the F flipped rows ----------------
    {
      int F = pubF_lds;
      if (F > 0) {                         // uniform: skip flip-free windows
        const float* Jb = J + 4 * (size_t)tid;
#pragma unroll
        for (int b = 0; b < WIN; b += 8) {
          if (b < F) {                     // uniform
            int4 r1 = *(const int4*)(pubi_lds + b);
            int4 r2 = *(const int4*)(pubi_lds + b + 4);
            float4 d1 = *(const float4*)(pubd_lds + b);
            float4 d2 = *(const float4*)(pubd_lds + b + 4);
            int rr[8] = {r1.x, r1.y, r1.z, r1.w, r2.x, r2.y, r2.z, r2.w};
            float dd[8] = {d1.x, d1.y, d1.z, d1.w, d2.x, d2.y, d2.z, d2.w};
            float4 rv[8];
            // loads first (back-to-back issue, one latency exposure per batch)
#pragma unroll
            for (int t = 0; t < 8; ++t)
              if (b + t < F) rv[t] = *(const float4*)(Jb + (size_t)rr[t] * N);
            float a0 = 0.f, a1 = 0.f, a2 = 0.f, a3 = 0.f;
#pragma unroll
            for (int t = 0; t < 8; ++t)
              if (b + t < F) {
                a0 += rv[t].x * dd[t]; a1 += rv[t].y * dd[t];
                a2 += rv[t].z * dd[t]; a3 += rv[t].w * dd[t];
              }
            // batch-local exact fp32 partials -> fp64 master
            i0 += (double)a0; i1 += (double)a1;
            i2 += (double)a2; i3 += (double)a3;
          }
        }
        *(double2*)(field_lds + 4 * tid + 0) = make_double2(i0, i1);
        *(double2*)(field_lds + 4 * tid + 2) = make_double2(i2, i3);
      }
      // wave0: store sliceB of G(k+1) (wait overlapped with the applies above)
      if (tid < 64) {
        float* dst = &STb[(k + 1) & 1][(32 + grow_r) * SBS64 + ghalf];
#pragma unroll
        for (int q = 0; q < 32; ++q) dst[q] = gva[q];
      }
    }
    lgkm_barrier();
  }

  __syncthreads();
  ((float4*)out)[tid] = ((const float4*)m_lds)[tid];
}

extern "C" void kernel_launch(void* const* d_in, const int* in_sizes, int n_in,
                              void* d_out, int out_size, void* d_ws, size_t ws_size,
                              hipStream_t stream) {
  const float* J = (const float*)d_in[0];
  const float* h = (const float*)d_in[1];
  const float* m0 = (const float*)d_in[2];
  const int* idx = (const int*)d_in[3];
  const float* u = (const float*)d_in[4];
  float* out = (float*)d_out;

  double* thr = (double*)d_ws;                                        // 16384 f64
  double* I0 = (double*)((char*)d_ws + STEPS * sizeof(double));       // 4096 f64
  unsigned long long* samemask =
      (unsigned long long*)((char*)d_ws + STEPS * sizeof(double)
                                        + N * sizeof(double));        // 16384 u64

  pre_kernel<<<dim3(STEPS / 256), dim3(256), 0, stream>>>(u, idx, thr, samemask);
  init_field_kernel<<<dim3(N), dim3(256), 0, stream>>>(J, h, m0, I0);
  pbit_kernel<<<dim3(1), dim3(MBLK), 0, stream>>>(J, m0, idx, thr, samemask, I0, out);
}

// Round 10
// 1675.480 us; speedup vs baseline: 1.6781x; 1.6781x over previous
//
#include <hip/hip_runtime.h>
#include <math.h>

#define N 4096
#define STEPS 16384
#define WIN 32                 // steps resolved per barrier pair
#define NWIN (STEPS / WIN)
#define MBLK 1024
#define SBS 36   // padded stride (floats) for the 32x32 coupling block (float4-aligned)

// Workgroup barrier that does NOT drain vmcnt (LDS-only ordering between phases).
__device__ __forceinline__ void lgkm_barrier() {
  asm volatile("s_waitcnt lgkmcnt(0)\n\ts_barrier" ::: "memory");
}

// ---- prep: thr[t] = atanh(2u-1) in fp64; samemask[t] = window bits with same idx ----
__global__ __launch_bounds__(256) void pre_kernel(const float* __restrict__ u,
                                                  const int* __restrict__ idx,
                                                  double* __restrict__ thr,
                                                  int* __restrict__ samemask) {
  int t = blockIdx.x * 256 + threadIdx.x;
  if (t < STEPS) {
    float r = 2.0f * u[t] - 1.0f;          // exact same fp32 rounding as reference
    double rd = (double)r;
    thr[t] = 0.5 * log((1.0 + rd) / (1.0 - rd));   // r=-1 -> -inf (tie->+1 matches ref)
    int cbase = t & ~(WIN - 1);
    int my = idx[t];
    unsigned int sm = 0u;
    for (int q = 0; q < WIN; ++q)
      if (idx[cbase + q] == my) sm |= (1u << q);   // includes self bit
    samemask[t] = (int)sm;
  }
}

// ---- initial field: I0[row] = sum_k J[row,k]*m0[k] + h[row], fp64 accumulate ----
__global__ __launch_bounds__(256) void init_field_kernel(const float* __restrict__ J,
                                                         const float* __restrict__ h,
                                                         const float* __restrict__ m0,
                                                         double* __restrict__ I) {
  __shared__ double red[256];
  int row = blockIdx.x;
  const float4* Jr = (const float4*)(J + (size_t)row * N);
  const float4* mv = (const float4*)m0;
  double acc = 0.0;
  for (int q = threadIdx.x; q < N / 4; q += 256) {
    float4 a = Jr[q];
    float4 b = mv[q];
    acc += (double)(a.x * b.x) + (double)(a.y * b.y) +
           (double)(a.z * b.z) + (double)(a.w * b.w);
  }
  red[threadIdx.x] = acc;
  __syncthreads();
  for (int s = 128; s > 0; s >>= 1) {
    if (threadIdx.x < s) red[threadIdx.x] += red[threadIdx.x + s];
    __syncthreads();
  }
  if (threadIdx.x == 0) I[row] = red[0] + (double)h[row];
}

// ---- window-resolved Glauber chain: 1 workgroup, 1024 threads, WIN=32 ----
// R8 champion + depth-2 column speculation on the resolve chain:
//  flips process in increasing f, and the candidate mask rarely changes, so the
//  next 1-2 candidate columns are prefetched (independent conflict-free
//  ds_read_b32, issued off-chain) and reused on hit -> the ~120cy LDS latency
//  overlaps the ballot/FMA chain instead of sitting on it.
// Also: m_lds[mi] for window k+1 is read in P1(k) right after publish (same-wave
// DS ordering), removing one chain-head LDS exposure.
__global__ __launch_bounds__(MBLK) void pbit_kernel(const float* __restrict__ J,
                                                    const float* __restrict__ m0,
                                                    const int* __restrict__ idx,
                                                    const double* __restrict__ thr,
                                                    const int* __restrict__ samemask,
                                                    const double* __restrict__ I0,
                                                    float* __restrict__ out) {
  __shared__ __align__(16) double field_lds[N];        // 32 KB master field
  __shared__ __align__(16) float m_lds[N];             // 16 KB spins
  __shared__ __align__(16) float STb[2][WIN * SBS];    // double-buffered 32x32 blocks
  __shared__ __align__(16) int   pubi_lds[WIN];        // compacted flip rows
  __shared__ __align__(16) float pubd_lds[WIN];        // compacted deltas (+/-2)
  __shared__ int pubF_lds;                             // flip count

  const int tid = threadIdx.x;

  // owned field elements 4*tid..4*tid+3: fp64 registers + LDS write-through
  double i0, i1, i2, i3;
  {
    const double* ip = I0 + 4 * tid;
    i0 = ip[0]; i1 = ip[1]; i2 = ip[2]; i3 = ip[3];
    *(double2*)(field_lds + 4 * tid + 0) = make_double2(i0, i1);
    *(double2*)(field_lds + 4 * tid + 2) = make_double2(i2, i3);
  }
  ((float4*)m_lds)[tid] = ((const float4*)m0)[tid];

  const int t32 = tid & 31;      // step slot within window (lanes 32-63 duplicate)
  const int jrow = tid >> 1;     // gather row slot (wave0: 0..31)
  const int half = (tid & 1) * 16;  // gather col half

  // wave0 step-data pipeline (3 windows deep) + in-flight gather registers
  int mi = 0, ni = 0, p2i = 0;
  unsigned int msm = 0u, nsm = 0u, p2sm = 0u;
  double mt = 0.0, nt = 0.0, p2t = 0.0;
  float mcur_next = 0.0f;        // m_lds[mi] for the upcoming window (hoisted)
  float4 gvA, gvB, gvC, gvD;     // G(k+2) values in flight (named: reg-resident)
  gvA = gvB = gvC = gvD = make_float4(0.f, 0.f, 0.f, 0.f);

  if (tid < 64) {
    mi  = idx[t32];           mt  = thr[t32];           msm  = (unsigned int)samemask[t32];
    ni  = idx[WIN + t32];     nt  = thr[WIN + t32];     nsm  = (unsigned int)samemask[WIN + t32];
    p2i = idx[2 * WIN + t32]; p2t = thr[2 * WIN + t32]; p2sm = (unsigned int)samemask[2 * WIN + t32];
    // sync gather G(0) -> STb[0]
    {
      int r0 = __shfl(mi, jrow);
      const float* Jr = J + (size_t)r0 * N;
#pragma unroll
      for (int q = 0; q < 16; ++q) {
        int c = __shfl(mi, half + q);
        STb[0][jrow * SBS + half + q] = Jr[c];
      }
    }
    // issue gather G(1) -> gv regs (drained by __syncthreads; stored at P1(0))
    {
      int r1 = __shfl(ni, jrow);
      const float* Jg = J + (size_t)r1 * N;
      int c0  = __shfl(ni, half + 0),  c1  = __shfl(ni, half + 1);
      int c2  = __shfl(ni, half + 2),  c3  = __shfl(ni, half + 3);
      int c4  = __shfl(ni, half + 4),  c5  = __shfl(ni, half + 5);
      int c6  = __shfl(ni, half + 6),  c7  = __shfl(ni, half + 7);
      int c8  = __shfl(ni, half + 8),  c9  = __shfl(ni, half + 9);
      int c10 = __shfl(ni, half + 10), c11 = __shfl(ni, half + 11);
      int c12 = __shfl(ni, half + 12), c13 = __shfl(ni, half + 13);
      int c14 = __shfl(ni, half + 14), c15 = __shfl(ni, half + 15);
      gvA = make_float4(Jg[c0],  Jg[c1],  Jg[c2],  Jg[c3]);
      gvB = make_float4(Jg[c4],  Jg[c5],  Jg[c6],  Jg[c7]);
      gvC = make_float4(Jg[c8],  Jg[c9],  Jg[c10], Jg[c11]);
      gvD = make_float4(Jg[c12], Jg[c13], Jg[c14], Jg[c15]);
    }
  }
  __syncthreads();
  if (tid < 64) mcur_next = m_lds[mi];   // spin for window 0

  for (int k = 0; k < NWIN; ++k) {
    // ---------------- P1: wave0 resolves 32 steps ----------------
    if (tid < 64) {
      // (a) store G(k+1) -> STb[(k+1)&1]  (issued one full window ago)
      {
        float* dst = &STb[(k + 1) & 1][jrow * SBS + half];
        *(float4*)(dst + 0)  = gvA;
        *(float4*)(dst + 4)  = gvB;
        *(float4*)(dst + 8)  = gvC;
        *(float4*)(dst + 12) = gvD;
      }
      // (b) issue G(k+2): rows/cols from p2i (consumed at P1(k+1) store)
      {
        int grow = __shfl(p2i, jrow);
        const float* Jg = J + (size_t)grow * N;
        int c0  = __shfl(p2i, half + 0),  c1  = __shfl(p2i, half + 1);
        int c2  = __shfl(p2i, half + 2),  c3  = __shfl(p2i, half + 3);
        int c4  = __shfl(p2i, half + 4),  c5  = __shfl(p2i, half + 5);
        int c6  = __shfl(p2i, half + 6),  c7  = __shfl(p2i, half + 7);
        int c8  = __shfl(p2i, half + 8),  c9  = __shfl(p2i, half + 9);
        int c10 = __shfl(p2i, half + 10), c11 = __shfl(p2i, half + 11);
        int c12 = __shfl(p2i, half + 12), c13 = __shfl(p2i, half + 13);
        int c14 = __shfl(p2i, half + 14), c15 = __shfl(p2i, half + 15);
        gvA = make_float4(Jg[c0],  Jg[c1],  Jg[c2],  Jg[c3]);
        gvB = make_float4(Jg[c4],  Jg[c5],  Jg[c6],  Jg[c7]);
        gvC = make_float4(Jg[c8],  Jg[c9],  Jg[c10], Jg[c11]);
        gvD = make_float4(Jg[c12], Jg[c13], Jg[c14], Jg[c15]);
      }
      // (c) step-data loads for window k+3
      int b3 = (k + 3) * WIN; if (b3 >= STEPS) b3 = 0;   // clamp: unused on tail
      int n3i = idx[b3 + t32];
      double n3t = thr[b3 + t32];
      unsigned int n3sm = (unsigned int)samemask[b3 + t32];
      // (d) flip-driven resolve from STb[k&1]: slim chain + depth-2 speculation
      const float* SB = &STb[k & 1][0];
      double Ival = field_lds[mi];
      float mcur = mcur_next;
      float finals = 0.0f, finald = 0.0f;
      int conf = -1;
      bool locked = false;
      int pf0 = -1, pf1 = -1;        // speculated next candidates
      float pv0 = 0.0f, pv1 = 0.0f;  // their prefetched columns
      while (true) {
        bool sup = (Ival >= mt);                 // I >= atanh(r) <=> tanh(I) >= r
        float s = sup ? 1.0f : -1.0f;
        float dl = s - mcur;
        unsigned int D = (unsigned int)__ballot(sup);   // lanes 32-63 mirror 0-31
        unsigned long long mask = __ballot(dl != 0.0f) & 0xFFFFFFFFull;
        mask &= (~0ull) << (conf + 1);
        if (mask == 0) {
          if (!locked) { finals = s; finald = 0.0f; }
          break;
        }
        int f = (int)__builtin_ctzll(mask);      // wave-uniform
        if (!locked && t32 <= f) { finals = s; finald = dl; locked = true; }
        // column for flip f: speculation hit -> register; miss -> fresh ds_read
        float xcol = (f == pf0) ? pv0 : ((f == pf1) ? pv1 : SB[f * SBS + t32]);
        // prefetch the next two candidates (independent conflict-free reads;
        // latency overlaps the FMA + next round's cmp/ballots)
        {
          unsigned long long m2 = mask & (mask - 1);
          unsigned long long m3 = m2 & (m2 - 1);
          int q0 = m2 ? (int)__builtin_ctzll(m2) : 0;
          int q1 = m3 ? (int)__builtin_ctzll(m3) : 0;
          pv0 = SB[q0 * SBS + t32];
          pv1 = SB[q1 * SBS + t32];
          pf0 = m2 ? q0 : -1;
          pf1 = m3 ? q1 : -1;
        }
        // flip lane f: flipped => dl_f = 2*s_f; s_f from ballot bit
        float s_f  = ((D >> f) & 1u) ? 1.0f : -1.0f;
        float dl_f = 2.0f * s_f;
        Ival += (double)(xcol * dl_f);            // exact product: dl in {-2,2}
        if ((msm >> f) & 1u) mcur = s_f;          // same-idx step (incl. self)
        conf = f;
      }
      // (e) publish: compacted flip list + m updates (last occurrence wins)
      unsigned long long fm = __ballot((tid < WIN) && (finald != 0.0f));
      if (tid < WIN) {
        if (finald != 0.0f) {
          int pos = __popcll(fm & ((1ull << t32) - 1ull));
          pubi_lds[pos] = mi;
          pubd_lds[pos] = finald;
        }
        bool mlo = (msm & (0xFFFFFFFEu << t32)) == 0u;   // no later same-idx step
        if (mlo) m_lds[mi] = finals;
        if (tid == 0) pubF_lds = (int)__popcll(fm);
      }
      // hoisted spin read for window k+1 (sees this window's m writes: same-wave
      // DS ordering); full phase of slack before use
      mcur_next = m_lds[ni];
      // (f) rotate step-data pipeline
      mi  = ni;  mt  = nt;  msm  = nsm;
      ni  = p2i; nt  = p2t; nsm  = p2sm;
      p2i = n3i; p2t = n3t; p2sm = n3sm;
    }
    lgkm_barrier();

    // ---------------- P2: all threads apply the F flipped rows ----------------
    {
      int F = pubF_lds;
      if (F > 0) {                         // uniform: skip flip-free windows
        const float* Jb = J + 4 * (size_t)tid;
#pragma unroll
        for (int b = 0; b < WIN; b += 8) {
          if (b < F) {                     // uniform
            int4 r1 = *(const int4*)(pubi_lds + b);
            int4 r2 = *(const int4*)(pubi_lds + b + 4);
            float4 d1 = *(const float4*)(pubd_lds + b);
            float4 d2 = *(const float4*)(pubd_lds + b + 4);
            int rr[8] = {r1.x, r1.y, r1.z, r1.w, r2.x, r2.y, r2.z, r2.w};
            float dd[8] = {d1.x, d1.y, d1.z, d1.w, d2.x, d2.y, d2.z, d2.w};
            float4 rv[8];
            // loads first (back-to-back issue, one latency exposure per batch)
#pragma unroll
            for (int t = 0; t < 8; ++t)
              if (b + t < F) rv[t] = *(const float4*)(Jb + (size_t)rr[t] * N);
            float a0 = 0.f, a1 = 0.f, a2 = 0.f, a3 = 0.f;
#pragma unroll
            for (int t = 0; t < 8; ++t)
              if (b + t < F) {
                a0 += rv[t].x * dd[t]; a1 += rv[t].y * dd[t];
                a2 += rv[t].z * dd[t]; a3 += rv[t].w * dd[t];
              }
            // batch-local exact fp32 partials -> fp64 master
            i0 += (double)a0; i1 += (double)a1;
            i2 += (double)a2; i3 += (double)a3;
          }
        }
        *(double2*)(field_lds + 4 * tid + 0) = make_double2(i0, i1);
        *(double2*)(field_lds + 4 * tid + 2) = make_double2(i2, i3);
      }
    }
    lgkm_barrier();
  }

  __syncthreads();
  ((float4*)out)[tid] = ((const float4*)m_lds)[tid];
}

extern "C" void kernel_launch(void* const* d_in, const int* in_sizes, int n_in,
                              void* d_out, int out_size, void* d_ws, size_t ws_size,
                              hipStream_t stream) {
  const float* J = (const float*)d_in[0];
  const float* h = (const float*)d_in[1];
  const float* m0 = (const float*)d_in[2];
  const int* idx = (const int*)d_in[3];
  const float* u = (const float*)d_in[4];
  float* out = (float*)d_out;

  double* thr = (double*)d_ws;                                        // 16384 f64
  double* I0 = (double*)((char*)d_ws + STEPS * sizeof(double));       // 4096 f64
  int* samemask = (int*)((char*)d_ws + STEPS * sizeof(double)
                                     + N * sizeof(double));           // 16384 i32

  pre_kernel<<<dim3(STEPS / 256), dim3(256), 0, stream>>>(u, idx, thr, samemask);
  init_field_kernel<<<dim3(N), dim3(256), 0, stream>>>(J, h, m0, I0);
  pbit_kernel<<<dim3(1), dim3(MBLK), 0, stream>>>(J, m0, idx, thr, samemask, I0, out);
}

// Round 11
// 1639.062 us; speedup vs baseline: 1.7154x; 1.0222x over previous
//
#include <hip/hip_runtime.h>
#include <math.h>

#define N 4096
#define STEPS 16384
#define WIN 32                 // steps resolved per barrier pair
#define NWIN (STEPS / WIN)
#define MBLK 1024
#define SBS 36   // padded stride (floats) for the 32x32 coupling block (float4-aligned)

// Workgroup barrier that does NOT drain vmcnt (LDS-only ordering between phases).
__device__ __forceinline__ void lgkm_barrier() {
  asm volatile("s_waitcnt lgkmcnt(0)\n\ts_barrier" ::: "memory");
}

// ---- prep: thr[t] = atanh(2u-1) in fp64; samemask[t] = window bits with same idx ----
__global__ __launch_bounds__(256) void pre_kernel(const float* __restrict__ u,
                                                  const int* __restrict__ idx,
                                                  double* __restrict__ thr,
                                                  int* __restrict__ samemask) {
  int t = blockIdx.x * 256 + threadIdx.x;
  if (t < STEPS) {
    float r = 2.0f * u[t] - 1.0f;          // exact same fp32 rounding as reference
    double rd = (double)r;
    thr[t] = 0.5 * log((1.0 + rd) / (1.0 - rd));   // r=-1 -> -inf (tie->+1 matches ref)
    int cbase = t & ~(WIN - 1);
    int my = idx[t];
    unsigned int sm = 0u;
    for (int q = 0; q < WIN; ++q)
      if (idx[cbase + q] == my) sm |= (1u << q);   // includes self bit
    samemask[t] = (int)sm;
  }
}

// ---- initial field: I0[row] = sum_k J[row,k]*m0[k] + h[row], fp64 accumulate ----
__global__ __launch_bounds__(256) void init_field_kernel(const float* __restrict__ J,
                                                         const float* __restrict__ h,
                                                         const float* __restrict__ m0,
                                                         double* __restrict__ I) {
  __shared__ double red[256];
  int row = blockIdx.x;
  const float4* Jr = (const float4*)(J + (size_t)row * N);
  const float4* mv = (const float4*)m0;
  double acc = 0.0;
  for (int q = threadIdx.x; q < N / 4; q += 256) {
    float4 a = Jr[q];
    float4 b = mv[q];
    acc += (double)(a.x * b.x) + (double)(a.y * b.y) +
           (double)(a.z * b.z) + (double)(a.w * b.w);
  }
  red[threadIdx.x] = acc;
  __syncthreads();
  for (int s = 128; s > 0; s >>= 1) {
    if (threadIdx.x < s) red[threadIdx.x] += red[threadIdx.x + s];
    __syncthreads();
  }
  if (threadIdx.x == 0) I[row] = red[0] + (double)h[row];
}

// ---- window-resolved Glauber chain: 1 workgroup, 1024 threads, WIN=32 ----
// R8 champion (2-deep gather pipeline, slim resolve chain) + two micro-opts:
//  - chain-head hoist: m_lds[ni] for window k+1 read in P1(k) after publish
//    (same-wave DS ordering), removing one LDS exposure from resolve entry
//  - fused ballot: lanes 32-63 mirror lanes 0-31, so ONE 64-lane ballot carries
//    both votes (lo half: decision sign D; hi half: flip-candidate mask)
// P1: wave0 resolves 32 steps flip-driven; workers park at the barrier.
// P2: all 1024 threads apply the F flipped rows; barriers are lgkm-only.
__global__ __launch_bounds__(MBLK) void pbit_kernel(const float* __restrict__ J,
                                                    const float* __restrict__ m0,
                                                    const int* __restrict__ idx,
                                                    const double* __restrict__ thr,
                                                    const int* __restrict__ samemask,
                                                    const double* __restrict__ I0,
                                                    float* __restrict__ out) {
  __shared__ __align__(16) double field_lds[N];        // 32 KB master field
  __shared__ __align__(16) float m_lds[N];             // 16 KB spins
  __shared__ __align__(16) float STb[2][WIN * SBS];    // double-buffered 32x32 blocks
  __shared__ __align__(16) int   pubi_lds[WIN];        // compacted flip rows
  __shared__ __align__(16) float pubd_lds[WIN];        // compacted deltas (+/-2)
  __shared__ int pubF_lds;                             // flip count

  const int tid = threadIdx.x;

  // owned field elements 4*tid..4*tid+3: fp64 registers + LDS write-through
  double i0, i1, i2, i3;
  {
    const double* ip = I0 + 4 * tid;
    i0 = ip[0]; i1 = ip[1]; i2 = ip[2]; i3 = ip[3];
    *(double2*)(field_lds + 4 * tid + 0) = make_double2(i0, i1);
    *(double2*)(field_lds + 4 * tid + 2) = make_double2(i2, i3);
  }
  ((float4*)m_lds)[tid] = ((const float4*)m0)[tid];

  const int t32 = tid & 31;      // step slot within window (lanes 32-63 duplicate)
  const int jrow = tid >> 1;     // gather row slot (wave0: 0..31)
  const int half = (tid & 1) * 16;  // gather col half

  // wave0 step-data pipeline (3 windows deep) + in-flight gather registers
  int mi = 0, ni = 0, p2i = 0;
  unsigned int msm = 0u, nsm = 0u, p2sm = 0u;
  double mt = 0.0, nt = 0.0, p2t = 0.0;
  float mcur_next = 0.0f;        // m_lds[mi] for the upcoming window (hoisted)
  float4 gvA, gvB, gvC, gvD;     // G(k+2) values in flight (named: reg-resident)
  gvA = gvB = gvC = gvD = make_float4(0.f, 0.f, 0.f, 0.f);

  if (tid < 64) {
    mi  = idx[t32];           mt  = thr[t32];           msm  = (unsigned int)samemask[t32];
    ni  = idx[WIN + t32];     nt  = thr[WIN + t32];     nsm  = (unsigned int)samemask[WIN + t32];
    p2i = idx[2 * WIN + t32]; p2t = thr[2 * WIN + t32]; p2sm = (unsigned int)samemask[2 * WIN + t32];
    // sync gather G(0) -> STb[0]
    {
      int r0 = __shfl(mi, jrow);
      const float* Jr = J + (size_t)r0 * N;
#pragma unroll
      for (int q = 0; q < 16; ++q) {
        int c = __shfl(mi, half + q);
        STb[0][jrow * SBS + half + q] = Jr[c];
      }
    }
    // issue gather G(1) -> gv regs (drained by __syncthreads; stored at P1(0))
    {
      int r1 = __shfl(ni, jrow);
      const float* Jg = J + (size_t)r1 * N;
      int c0  = __shfl(ni, half + 0),  c1  = __shfl(ni, half + 1);
      int c2  = __shfl(ni, half + 2),  c3  = __shfl(ni, half + 3);
      int c4  = __shfl(ni, half + 4),  c5  = __shfl(ni, half + 5);
      int c6  = __shfl(ni, half + 6),  c7  = __shfl(ni, half + 7);
      int c8  = __shfl(ni, half + 8),  c9  = __shfl(ni, half + 9);
      int c10 = __shfl(ni, half + 10), c11 = __shfl(ni, half + 11);
      int c12 = __shfl(ni, half + 12), c13 = __shfl(ni, half + 13);
      int c14 = __shfl(ni, half + 14), c15 = __shfl(ni, half + 15);
      gvA = make_float4(Jg[c0],  Jg[c1],  Jg[c2],  Jg[c3]);
      gvB = make_float4(Jg[c4],  Jg[c5],  Jg[c6],  Jg[c7]);
      gvC = make_float4(Jg[c8],  Jg[c9],  Jg[c10], Jg[c11]);
      gvD = make_float4(Jg[c12], Jg[c13], Jg[c14], Jg[c15]);
    }
  }
  __syncthreads();
  if (tid < 64) mcur_next = m_lds[mi];   // spin for window 0

  for (int k = 0; k < NWIN; ++k) {
    // ---------------- P1: wave0 resolves 32 steps ----------------
    if (tid < 64) {
      // (a) store G(k+1) -> STb[(k+1)&1]  (issued one full window ago)
      {
        float* dst = &STb[(k + 1) & 1][jrow * SBS + half];
        *(float4*)(dst + 0)  = gvA;
        *(float4*)(dst + 4)  = gvB;
        *(float4*)(dst + 8)  = gvC;
        *(float4*)(dst + 12) = gvD;
      }
      // (b) issue G(k+2): rows/cols from p2i (consumed at P1(k+1) store)
      {
        int grow = __shfl(p2i, jrow);
        const float* Jg = J + (size_t)grow * N;
        int c0  = __shfl(p2i, half + 0),  c1  = __shfl(p2i, half + 1);
        int c2  = __shfl(p2i, half + 2),  c3  = __shfl(p2i, half + 3);
        int c4  = __shfl(p2i, half + 4),  c5  = __shfl(p2i, half + 5);
        int c6  = __shfl(p2i, half + 6),  c7  = __shfl(p2i, half + 7);
        int c8  = __shfl(p2i, half + 8),  c9  = __shfl(p2i, half + 9);
        int c10 = __shfl(p2i, half + 10), c11 = __shfl(p2i, half + 11);
        int c12 = __shfl(p2i, half + 12), c13 = __shfl(p2i, half + 13);
        int c14 = __shfl(p2i, half + 14), c15 = __shfl(p2i, half + 15);
        gvA = make_float4(Jg[c0],  Jg[c1],  Jg[c2],  Jg[c3]);
        gvB = make_float4(Jg[c4],  Jg[c5],  Jg[c6],  Jg[c7]);
        gvC = make_float4(Jg[c8],  Jg[c9],  Jg[c10], Jg[c11]);
        gvD = make_float4(Jg[c12], Jg[c13], Jg[c14], Jg[c15]);
      }
      // (c) step-data loads for window k+3
      int b3 = (k + 3) * WIN; if (b3 >= STEPS) b3 = 0;   // clamp: unused on tail
      int n3i = idx[b3 + t32];
      double n3t = thr[b3 + t32];
      unsigned int n3sm = (unsigned int)samemask[b3 + t32];
      // (d) flip-driven resolve from STb[k&1]: slim chain, fused single ballot
      const float* SB = &STb[k & 1][0];
      double Ival = field_lds[mi];
      float mcur = mcur_next;
      float finals = 0.0f, finald = 0.0f;
      int conf = -1;
      bool locked = false;
      while (true) {
        bool sup = (Ival >= mt);                 // I >= atanh(r) <=> tanh(I) >= r
        float s = sup ? 1.0f : -1.0f;
        float dl = s - mcur;
        // ONE 64-lane ballot: lo half votes decision sign, hi half votes flip
        bool pred = (tid >= 32) ? (dl != 0.0f) : sup;
        unsigned long long B = __ballot(pred);
        unsigned int D = (unsigned int)(B & 0xFFFFFFFFull);
        unsigned long long mask = (B >> 32) & ((~0ull) << (conf + 1));
        if (mask == 0ull) {
          if (!locked) { finals = s; finald = 0.0f; }
          break;
        }
        int f = (int)__builtin_ctzll(mask);      // wave-uniform
        if (!locked && t32 <= f) { finals = s; finald = dl; locked = true; }
        // flip lane f: flipped => dl_f = 2*s_f; s_f from ballot bit
        float s_f  = ((D >> f) & 1u) ? 1.0f : -1.0f;
        float dl_f = 2.0f * s_f;
        // Scol[f] for my lane = SB[f*SBS + t32]: conflict-free ds_read, f uniform
        float xcol = SB[f * SBS + t32];
        Ival += (double)(xcol * dl_f);            // exact product: dl in {-2,2}
        if ((msm >> f) & 1u) mcur = s_f;          // same-idx step (incl. self)
        conf = f;
      }
      // (e) publish: compacted flip list + m updates (last occurrence wins)
      unsigned long long fm = __ballot((tid < WIN) && (finald != 0.0f));
      if (tid < WIN) {
        if (finald != 0.0f) {
          int pos = __popcll(fm & ((1ull << t32) - 1ull));
          pubi_lds[pos] = mi;
          pubd_lds[pos] = finald;
        }
        bool mlo = (msm & (0xFFFFFFFEu << t32)) == 0u;   // no later same-idx step
        if (mlo) m_lds[mi] = finals;
        if (tid == 0) pubF_lds = (int)__popcll(fm);
      }
      // hoisted spin read for window k+1 (sees this window's m writes: same-wave
      // DS ordering); full phase of slack before its use at next P1
      mcur_next = m_lds[ni];
      // (f) rotate step-data pipeline
      mi  = ni;  mt  = nt;  msm  = nsm;
      ni  = p2i; nt  = p2t; nsm  = p2sm;
      p2i = n3i; p2t = n3t; p2sm = n3sm;
    }
    lgkm_barrier();

    // ---------------- P2: all threads apply the F flipped rows ----------------
    {
      int F = pubF_lds;
      if (F > 0) {                         // uniform: skip flip-free windows
        const float* Jb = J + 4 * (size_t)tid;
#pragma unroll
        for (int b = 0; b < WIN; b += 8) {
          if (b < F) {                     // uniform
            int4 r1 = *(const int4*)(pubi_lds + b);
            int4 r2 = *(const int4*)(pubi_lds + b + 4);
            float4 d1 = *(const float4*)(pubd_lds + b);
            float4 d2 = *(const float4*)(pubd_lds + b + 4);
            int rr[8] = {r1.x, r1.y, r1.z, r1.w, r2.x, r2.y, r2.z, r2.w};
            float dd[8] = {d1.x, d1.y, d1.z, d1.w, d2.x, d2.y, d2.z, d2.w};
            float4 rv[8];
            // loads first (back-to-back issue, one latency exposure per batch)
#pragma unroll
            for (int t = 0; t < 8; ++t)
              if (b + t < F) rv[t] = *(const float4*)(Jb + (size_t)rr[t] * N);
            float a0 = 0.f, a1 = 0.f, a2 = 0.f, a3 = 0.f;
#pragma unroll
            for (int t = 0; t < 8; ++t)
              if (b + t < F) {
                a0 += rv[t].x * dd[t]; a1 += rv[t].y * dd[t];
                a2 += rv[t].z * dd[t]; a3 += rv[t].w * dd[t];
              }
            // batch-local exact fp32 partials -> fp64 master
            i0 += (double)a0; i1 += (double)a1;
            i2 += (double)a2; i3 += (double)a3;
          }
        }
        *(double2*)(field_lds + 4 * tid + 0) = make_double2(i0, i1);
        *(double2*)(field_lds + 4 * tid + 2) = make_double2(i2, i3);
      }
    }
    lgkm_barrier();
  }

  __syncthreads();
  ((float4*)out)[tid] = ((const float4*)m_lds)[tid];
}

extern "C" void kernel_launch(void* const* d_in, const int* in_sizes, int n_in,
                              void* d_out, int out_size, void* d_ws, size_t ws_size,
                              hipStream_t stream) {
  const float* J = (const float*)d_in[0];
  const float* h = (const float*)d_in[1];
  const float* m0 = (const float*)d_in[2];
  const int* idx = (const int*)d_in[3];
  const float* u = (const float*)d_in[4];
  float* out = (float*)d_out;

  double* thr = (double*)d_ws;                                        // 16384 f64
  double* I0 = (double*)((char*)d_ws + STEPS * sizeof(double));       // 4096 f64
  int* samemask = (int*)((char*)d_ws + STEPS * sizeof(double)
                                     + N * sizeof(double));           // 16384 i32

  pre_kernel<<<dim3(STEPS / 256), dim3(256), 0, stream>>>(u, idx, thr, samemask);
  init_field_kernel<<<dim3(N), dim3(256), 0, stream>>>(J, h, m0, I0);
  pbit_kernel<<<dim3(1), dim3(MBLK), 0, stream>>>(J, m0, idx, thr, samemask, I0, out);
}

// Round 12
// 1622.786 us; speedup vs baseline: 1.7326x; 1.0100x over previous
//
#include <hip/hip_runtime.h>
#include <math.h>

#define N 4096
#define STEPS 16384
#define WIN 32                 // steps resolved per barrier pair
#define NWIN (STEPS / WIN)
#define MBLK 1024
#define SBS 36   // padded stride (floats) for the 32x32 coupling block (float4-aligned)

// Workgroup barrier that does NOT drain vmcnt (LDS-only ordering between phases).
__device__ __forceinline__ void lgkm_barrier() {
  asm volatile("s_waitcnt lgkmcnt(0)\n\ts_barrier" ::: "memory");
}

// ---- prep: thr[t] = atanh(2u-1) in fp64; samemask[t] = window bits with same idx ----
__global__ __launch_bounds__(256) void pre_kernel(const float* __restrict__ u,
                                                  const int* __restrict__ idx,
                                                  double* __restrict__ thr,
                                                  int* __restrict__ samemask) {
  int t = blockIdx.x * 256 + threadIdx.x;
  if (t < STEPS) {
    float r = 2.0f * u[t] - 1.0f;          // exact same fp32 rounding as reference
    double rd = (double)r;
    thr[t] = 0.5 * log((1.0 + rd) / (1.0 - rd));   // r=-1 -> -inf (tie->+1 matches ref)
    int cbase = t & ~(WIN - 1);
    int my = idx[t];
    unsigned int sm = 0u;
    for (int q = 0; q < WIN; ++q)
      if (idx[cbase + q] == my) sm |= (1u << q);   // includes self bit
    samemask[t] = (int)sm;
  }
}

// ---- initial field: I0[row] = sum_k J[row,k]*m0[k] + h[row], fp64 accumulate ----
__global__ __launch_bounds__(256) void init_field_kernel(const float* __restrict__ J,
                                                         const float* __restrict__ h,
                                                         const float* __restrict__ m0,
                                                         double* __restrict__ I) {
  __shared__ double red[256];
  int row = blockIdx.x;
  const float4* Jr = (const float4*)(J + (size_t)row * N);
  const float4* mv = (const float4*)m0;
  double acc = 0.0;
  for (int q = threadIdx.x; q < N / 4; q += 256) {
    float4 a = Jr[q];
    float4 b = mv[q];
    acc += (double)(a.x * b.x) + (double)(a.y * b.y) +
           (double)(a.z * b.z) + (double)(a.w * b.w);
  }
  red[threadIdx.x] = acc;
  __syncthreads();
  for (int s = 128; s > 0; s >>= 1) {
    if (threadIdx.x < s) red[threadIdx.x] += red[threadIdx.x + s];
    __syncthreads();
  }
  if (threadIdx.x == 0) I[row] = red[0] + (double)h[row];
}

// ---- window-resolved Glauber chain: 1 workgroup, 1024 threads, WIN=32 ----
// Champion structure (R8, 1536 us):
//  P1(k): (a) STORE G(k+1) (gathered at P1(k-1): one full window of slack, so
//             the divergent-gather TA time + vmcnt wait is off the serial path)
//         (b) ISSUE G(k+2) from the 3-deep index pipeline (p2i)
//         (c) resolve window k from STb[k&1] (slim chain: ballot-bit signs,
//             samemask dup update, one conflict-free ds_read per flip)
//  Workers park at the barrier during P1 (proven regime).
//  P2: all 1024 threads apply the F flipped rows; barriers are lgkm-only.
__global__ __launch_bounds__(MBLK) void pbit_kernel(const float* __restrict__ J,
                                                    const float* __restrict__ m0,
                                                    const int* __restrict__ idx,
                                                    const double* __restrict__ thr,
                                                    const int* __restrict__ samemask,
                                                    const double* __restrict__ I0,
                                                    float* __restrict__ out) {
  __shared__ __align__(16) double field_lds[N];        // 32 KB master field
  __shared__ __align__(16) float m_lds[N];             // 16 KB spins
  __shared__ __align__(16) float STb[2][WIN * SBS];    // double-buffered 32x32 blocks
  __shared__ __align__(16) int   pubi_lds[WIN];        // compacted flip rows
  __shared__ __align__(16) float pubd_lds[WIN];        // compacted deltas (+/-2)
  __shared__ int pubF_lds;                             // flip count

  const int tid = threadIdx.x;

  // owned field elements 4*tid..4*tid+3: fp64 registers + LDS write-through
  double i0, i1, i2, i3;
  {
    const double* ip = I0 + 4 * tid;
    i0 = ip[0]; i1 = ip[1]; i2 = ip[2]; i3 = ip[3];
    *(double2*)(field_lds + 4 * tid + 0) = make_double2(i0, i1);
    *(double2*)(field_lds + 4 * tid + 2) = make_double2(i2, i3);
  }
  ((float4*)m_lds)[tid] = ((const float4*)m0)[tid];

  const int t32 = tid & 31;      // step slot within window (lanes 32-63 duplicate)
  const int jrow = tid >> 1;     // gather row slot (wave0: 0..31)
  const int half = (tid & 1) * 16;  // gather col half

  // wave0 step-data pipeline (3 windows deep) + in-flight gather registers
  int mi = 0, ni = 0, p2i = 0;
  unsigned int msm = 0u, nsm = 0u, p2sm = 0u;
  double mt = 0.0, nt = 0.0, p2t = 0.0;
  float4 gvA, gvB, gvC, gvD;     // G(k+2) values in flight (named: reg-resident)
  gvA = gvB = gvC = gvD = make_float4(0.f, 0.f, 0.f, 0.f);

  if (tid < 64) {
    mi  = idx[t32];           mt  = thr[t32];           msm  = (unsigned int)samemask[t32];
    ni  = idx[WIN + t32];     nt  = thr[WIN + t32];     nsm  = (unsigned int)samemask[WIN + t32];
    p2i = idx[2 * WIN + t32]; p2t = thr[2 * WIN + t32]; p2sm = (unsigned int)samemask[2 * WIN + t32];
    // sync gather G(0) -> STb[0]
    {
      int r0 = __shfl(mi, jrow);
      const float* Jr = J + (size_t)r0 * N;
#pragma unroll
      for (int q = 0; q < 16; ++q) {
        int c = __shfl(mi, half + q);
        STb[0][jrow * SBS + half + q] = Jr[c];
      }
    }
    // issue gather G(1) -> gv regs (drained by __syncthreads; stored at P1(0))
    {
      int r1 = __shfl(ni, jrow);
      const float* Jg = J + (size_t)r1 * N;
      int c0  = __shfl(ni, half + 0),  c1  = __shfl(ni, half + 1);
      int c2  = __shfl(ni, half + 2),  c3  = __shfl(ni, half + 3);
      int c4  = __shfl(ni, half + 4),  c5  = __shfl(ni, half + 5);
      int c6  = __shfl(ni, half + 6),  c7  = __shfl(ni, half + 7);
      int c8  = __shfl(ni, half + 8),  c9  = __shfl(ni, half + 9);
      int c10 = __shfl(ni, half + 10), c11 = __shfl(ni, half + 11);
      int c12 = __shfl(ni, half + 12), c13 = __shfl(ni, half + 13);
      int c14 = __shfl(ni, half + 14), c15 = __shfl(ni, half + 15);
      gvA = make_float4(Jg[c0],  Jg[c1],  Jg[c2],  Jg[c3]);
      gvB = make_float4(Jg[c4],  Jg[c5],  Jg[c6],  Jg[c7]);
      gvC = make_float4(Jg[c8],  Jg[c9],  Jg[c10], Jg[c11]);
      gvD = make_float4(Jg[c12], Jg[c13], Jg[c14], Jg[c15]);
    }
  }
  __syncthreads();

  for (int k = 0; k < NWIN; ++k) {
    // ---------------- P1: wave0 resolves 32 steps ----------------
    if (tid < 64) {
      // (a) store G(k+1) -> STb[(k+1)&1]  (issued one full window ago)
      {
        float* dst = &STb[(k + 1) & 1][jrow * SBS + half];
        *(float4*)(dst + 0)  = gvA;
        *(float4*)(dst + 4)  = gvB;
        *(float4*)(dst + 8)  = gvC;
        *(float4*)(dst + 12) = gvD;
      }
      // (b) issue G(k+2): rows/cols from p2i (consumed at P1(k+1) store)
      {
        int grow = __shfl(p2i, jrow);
        const float* Jg = J + (size_t)grow * N;
        int c0  = __shfl(p2i, half + 0),  c1  = __shfl(p2i, half + 1);
        int c2  = __shfl(p2i, half + 2),  c3  = __shfl(p2i, half + 3);
        int c4  = __shfl(p2i, half + 4),  c5  = __shfl(p2i, half + 5);
        int c6  = __shfl(p2i, half + 6),  c7  = __shfl(p2i, half + 7);
        int c8  = __shfl(p2i, half + 8),  c9  = __shfl(p2i, half + 9);
        int c10 = __shfl(p2i, half + 10), c11 = __shfl(p2i, half + 11);
        int c12 = __shfl(p2i, half + 12), c13 = __shfl(p2i, half + 13);
        int c14 = __shfl(p2i, half + 14), c15 = __shfl(p2i, half + 15);
        gvA = make_float4(Jg[c0],  Jg[c1],  Jg[c2],  Jg[c3]);
        gvB = make_float4(Jg[c4],  Jg[c5],  Jg[c6],  Jg[c7]);
        gvC = make_float4(Jg[c8],  Jg[c9],  Jg[c10], Jg[c11]);
        gvD = make_float4(Jg[c12], Jg[c13], Jg[c14], Jg[c15]);
      }
      // (c) step-data loads for window k+3
      int b3 = (k + 3) * WIN; if (b3 >= STEPS) b3 = 0;   // clamp: unused on tail
      int n3i = idx[b3 + t32];
      double n3t = thr[b3 + t32];
      unsigned int n3sm = (unsigned int)samemask[b3 + t32];
      // (d) flip-driven resolve from STb[k&1]: slim chain
      const float* SB = &STb[k & 1][0];
      double Ival = field_lds[mi];
      float mcur = m_lds[mi];
      float finals = 0.0f, finald = 0.0f;
      int conf = -1;
      bool locked = false;
      while (true) {
        bool sup = (Ival >= mt);                 // I >= atanh(r) <=> tanh(I) >= r
        float s = sup ? 1.0f : -1.0f;
        float dl = s - mcur;
        unsigned int D = (unsigned int)__ballot(sup);   // lanes 32-63 mirror 0-31
        unsigned long long mask = __ballot(dl != 0.0f) & 0xFFFFFFFFull;
        mask &= (~0ull) << (conf + 1);
        if (mask == 0) {
          if (!locked) { finals = s; finald = 0.0f; }
          break;
        }
        int f = (int)__builtin_ctzll(mask);      // wave-uniform
        if (!locked && t32 <= f) { finals = s; finald = dl; locked = true; }
        // flip lane f: flipped => dl_f = 2*s_f; s_f from ballot bit
        float s_f  = ((D >> f) & 1u) ? 1.0f : -1.0f;
        float dl_f = 2.0f * s_f;
        // Scol[f] for my lane = SB[f*SBS + t32]: conflict-free ds_read, f uniform
        float xcol = SB[f * SBS + t32];
        Ival += (double)(xcol * dl_f);            // exact product: dl in {-2,2}
        if ((msm >> f) & 1u) mcur = s_f;          // same-idx step (incl. self)
        conf = f;
      }
      // (e) publish: compacted flip list + m updates (last occurrence wins)
      unsigned long long fm = __ballot((tid < WIN) && (finald != 0.0f));
      if (tid < WIN) {
        if (finald != 0.0f) {
          int pos = __popcll(fm & ((1ull << t32) - 1ull));
          pubi_lds[pos] = mi;
          pubd_lds[pos] = finald;
        }
        bool mlo = (msm & (0xFFFFFFFEu << t32)) == 0u;   // no later same-idx step
        if (mlo) m_lds[mi] = finals;
        if (tid == 0) pubF_lds = (int)__popcll(fm);
      }
      // (f) rotate step-data pipeline
      mi  = ni;  mt  = nt;  msm  = nsm;
      ni  = p2i; nt  = p2t; nsm  = p2sm;
      p2i = n3i; p2t = n3t; p2sm = n3sm;
    }
    lgkm_barrier();

    // ---------------- P2: all threads apply the F flipped rows ----------------
    {
      int F = pubF_lds;
      if (F > 0) {                         // uniform: skip flip-free windows
        const float* Jb = J + 4 * (size_t)tid;
#pragma unroll
        for (int b = 0; b < WIN; b += 8) {
          if (b < F) {                     // uniform
            int4 r1 = *(const int4*)(pubi_lds + b);
            int4 r2 = *(const int4*)(pubi_lds + b + 4);
            float4 d1 = *(const float4*)(pubd_lds + b);
            float4 d2 = *(const float4*)(pubd_lds + b + 4);
            int rr[8] = {r1.x, r1.y, r1.z, r1.w, r2.x, r2.y, r2.z, r2.w};
            float dd[8] = {d1.x, d1.y, d1.z, d1.w, d2.x, d2.y, d2.z, d2.w};
            float4 rv[8];
            // loads first (back-to-back issue, one latency exposure per batch)
#pragma unroll
            for (int t = 0; t < 8; ++t)
              if (b + t < F) rv[t] = *(const float4*)(Jb + (size_t)rr[t] * N);
            float a0 = 0.f, a1 = 0.f, a2 = 0.f, a3 = 0.f;
#pragma unroll
            for (int t = 0; t < 8; ++t)
              if (b + t < F) {
                a0 += rv[t].x * dd[t]; a1 += rv[t].y * dd[t];
                a2 += rv[t].z * dd[t]; a3 += rv[t].w * dd[t];
              }
            // batch-local exact fp32 partials -> fp64 master
            i0 += (double)a0; i1 += (double)a1;
            i2 += (double)a2; i3 += (double)a3;
          }
        }
        *(double2*)(field_lds + 4 * tid + 0) = make_double2(i0, i1);
        *(double2*)(field_lds + 4 * tid + 2) = make_double2(i2, i3);
      }
    }
    lgkm_barrier();
  }

  __syncthreads();
  ((float4*)out)[tid] = ((const float4*)m_lds)[tid];
}

extern "C" void kernel_launch(void* const* d_in, const int* in_sizes, int n_in,
                              void* d_out, int out_size, void* d_ws, size_t ws_size,
                              hipStream_t stream) {
  const float* J = (const float*)d_in[0];
  const float* h = (const float*)d_in[1];
  const float* m0 = (const float*)d_in[2];
  const int* idx = (const int*)d_in[3];
  const float* u = (const float*)d_in[4];
  float* out = (float*)d_out;

  double* thr = (double*)d_ws;                                        // 16384 f64
  double* I0 = (double*)((char*)d_ws + STEPS * sizeof(double));       // 4096 f64
  int* samemask = (int*)((char*)d_ws + STEPS * sizeof(double)
                                     + N * sizeof(double));           // 16384 i32

  pre_kernel<<<dim3(STEPS / 256), dim3(256), 0, stream>>>(u, idx, thr, samemask);
  init_field_kernel<<<dim3(N), dim3(256), 0, stream>>>(J, h, m0, I0);
  pbit_kernel<<<dim3(1), dim3(MBLK), 0, stream>>>(J, m0, idx, thr, samemask, I0, out);
}